// Round 8
// baseline (267.155 us; speedup 1.0000x reference)
//
#include <hip/hip_runtime.h>
#include <stdint.h>

// SRU layer fused pipeline (round 8):
//  1) prep:  fused [cvt: w_ufr f32->bf16] + [ln: LayerNorm -> x_norm bf16 +
//            per-row mu/rstd] in one dispatch (block-id split)
//  2) gemm:  r7-verified 256x256 / BK=32 / 4-slot ring / counted vmcnt /
//            XOR swizzle (0 conflicts) / XCD block swizzle. u -> bf16 [M][D],
//            f/r -> hardsigmoid u8 [M][D].
//  3) scan:  SINGLE-PASS fused scan (decoupled lookback): per (chunk, batch)
//            block computes local (A,B), publishes device-scope, looks back
//            for chunk-start c, then does recurrence + softsign + mix +
//            residual. Replaces scan1+scan2+scan3. Flags memset per call.

#define T_SEQ 2048
#define BATCH 8
#define DIM 1024
#define M_SZ (T_SEQ * BATCH)   // 16384
#define N_SZ (3 * DIM)         // 3072
#define K_SZ DIM               // 1024
#define NCHUNK 32
#define CLEN (T_SEQ / NCHUNK)  // 64

#define GBM 256
#define GBN 256
#define GBK 32
#define NKT (K_SZ / GBK)          // 32 K-steps
#define NBX (N_SZ / GBN)          // 12
#define NWG (NBX * (M_SZ / GBM))  // 768; 768 % 8 == 0 -> bijective XCD swizzle

#define CVT_BLOCKS ((N_SZ * K_SZ / 4) / 256)   // 3072

typedef __attribute__((ext_vector_type(8))) __bf16 bf16x8;
typedef __attribute__((ext_vector_type(4))) float f32x4;

__device__ __forceinline__ unsigned short f2bf(float f) {
  unsigned int u = __float_as_uint(f);
  u += 0x7FFFu + ((u >> 16) & 1u);   // round-to-nearest-even
  return (unsigned short)(u >> 16);
}
__device__ __forceinline__ float bf2f(unsigned short s) {
  return __uint_as_float(((unsigned int)s) << 16);
}
__device__ __forceinline__ void gload16(const void* g, void* l) {
  __builtin_amdgcn_global_load_lds(
      (__attribute__((address_space(1))) void*)const_cast<void*>(g),
      (__attribute__((address_space(3))) void*)l, 16, 0, 0);
}

// ---------------- 1) fused weight-cvt + LayerNorm ----------------
__global__ __launch_bounds__(256) void prep_kernel(const float* __restrict__ w,
                                                   unsigned short* __restrict__ wb,
                                                   const float* __restrict__ x,
                                                   const float* __restrict__ gamma,
                                                   const float* __restrict__ beta,
                                                   unsigned short* __restrict__ xn,
                                                   float* __restrict__ muO,
                                                   float* __restrict__ rsO) {
  const int tid = threadIdx.x;
  if (blockIdx.x < CVT_BLOCKS) {
    const int i = blockIdx.x * 256 + tid;
    const float4 v = reinterpret_cast<const float4*>(w)[i];
    ushort4 o;
    o.x = f2bf(v.x); o.y = f2bf(v.y); o.z = f2bf(v.z); o.w = f2bf(v.w);
    reinterpret_cast<ushort4*>(wb)[i] = o;
    return;
  }
  const int row = blockIdx.x - CVT_BLOCKS;
  const float4 v = reinterpret_cast<const float4*>(x + (size_t)row * DIM)[tid];
  float s = v.x + v.y + v.z + v.w;
  float q = v.x * v.x + v.y * v.y + v.z * v.z + v.w * v.w;
#pragma unroll
  for (int off = 32; off > 0; off >>= 1) {
    s += __shfl_down(s, off);
    q += __shfl_down(q, off);
  }
  __shared__ float sbuf[8];
  const int wv = tid >> 6, ln = tid & 63;
  if (ln == 0) { sbuf[wv] = s; sbuf[4 + wv] = q; }
  __syncthreads();
  s = sbuf[0] + sbuf[1] + sbuf[2] + sbuf[3];
  q = sbuf[4] + sbuf[5] + sbuf[6] + sbuf[7];
  const float mu = s * (1.0f / DIM);
  const float rstd = rsqrtf(q * (1.0f / DIM) - mu * mu + 1e-5f);
  if (tid == 0) { muO[row] = mu; rsO[row] = rstd; }
  const float4 g = reinterpret_cast<const float4*>(gamma)[tid];
  const float4 b = reinterpret_cast<const float4*>(beta)[tid];
  ushort4 o;
  o.x = f2bf((v.x - mu) * rstd * g.x + b.x);
  o.y = f2bf((v.y - mu) * rstd * g.y + b.y);
  o.z = f2bf((v.z - mu) * rstd * g.z + b.z);
  o.w = f2bf((v.w - mu) * rstd * g.w + b.w);
  reinterpret_cast<ushort4*>(xn + (size_t)row * DIM)[tid] = o;
}

// ---------------- 2) GEMM: C[m,n] = sum_k A[m,k] * W[n,k], bf16 MFMA ----------------
// r7-verified. 256x256 tile, BK=32, 512 threads (8 waves, 2Mx4N), 4-slot LDS
// ring, depth-3 prefetch, vmcnt(8) steady state, one s_barrier per K-step,
// XOR slot-swizzle (0 bank conflicts), XCD block swizzle.
__global__ __launch_bounds__(512) void gemm_kernel(const unsigned short* __restrict__ A,
                                                   const unsigned short* __restrict__ W,
                                                   unsigned short* __restrict__ U,
                                                   unsigned char* __restrict__ Fq,
                                                   unsigned char* __restrict__ Rq) {
  __shared__ unsigned short smem[2 * 4 * GBM * GBK];   // 131072 B
  const int tid = threadIdx.x;
  const int lane = tid & 63;
  const int wid = tid >> 6;                 // 0..7
  const int wm = wid >> 2, wn = wid & 3;    // 2 x 4 wave grid

  const int wg = (blockIdx.x & 7) * (NWG / 8) + (blockIdx.x >> 3);
  const int bn0 = (wg % NBX) * GBN;
  const int bm0 = (wg / NBX) * GBM;

  const int stgRow = wid * 32 + (lane >> 2);
  const int stgCol = ((lane & 3) ^ ((lane >> 3) & 3)) * 8;
  const unsigned short* gA = A + (size_t)(bm0 + stgRow) * K_SZ + stgCol;
  const unsigned short* gB = W + (size_t)(bn0 + stgRow) * K_SZ + stgCol;
  unsigned short* sAb = smem + wid * 32 * GBK;
  unsigned short* sBb = smem + 4 * GBM * GBK + wid * 32 * GBK;

#define STAGE(bufi, t) do {                                        \
    const size_t ko_ = (size_t)(t) * GBK;                          \
    unsigned short* sa_ = sAb + (bufi) * (GBM * GBK);              \
    unsigned short* sb_ = sBb + (bufi) * (GBM * GBK);              \
    gload16(gA + ko_, sa_);                                        \
    gload16(gA + ko_ + (size_t)16 * K_SZ, sa_ + 16 * GBK);         \
    gload16(gB + ko_, sb_);                                        \
    gload16(gB + ko_ + (size_t)16 * K_SZ, sb_ + 16 * GBK);         \
  } while (0)

  f32x4 acc[8][4] = {};
  const int fr = lane & 15;
  const int ko8 = ((lane >> 4) ^ ((fr >> 1) & 3)) * 8;

  STAGE(0, 0);
  STAGE(1, 1);
  STAGE(2, 2);
  asm volatile("s_waitcnt vmcnt(8)" ::: "memory");
  __builtin_amdgcn_s_barrier();
  asm volatile("" ::: "memory");

  for (int kt = 0; kt < NKT; ++kt) {
    const int cur = kt & 3;
    if (kt < NKT - 3) STAGE((kt + 3) & 3, kt + 3);

    const unsigned short* sa = smem + cur * (GBM * GBK);
    const unsigned short* sb = smem + 4 * GBM * GBK + cur * (GBM * GBK);
    bf16x8 af[8], bf[4];
#pragma unroll
    for (int i = 0; i < 8; i++)
      af[i] = *(const bf16x8*)&sa[(wm * 128 + i * 16 + fr) * GBK + ko8];
#pragma unroll
    for (int j = 0; j < 4; j++)
      bf[j] = *(const bf16x8*)&sb[(wn * 64 + j * 16 + fr) * GBK + ko8];

    __builtin_amdgcn_s_setprio(1);
#pragma unroll
    for (int i = 0; i < 8; i++)
#pragma unroll
      for (int j = 0; j < 4; j++)
        acc[i][j] = __builtin_amdgcn_mfma_f32_16x16x32_bf16(af[i], bf[j], acc[i][j], 0, 0, 0);
    __builtin_amdgcn_s_setprio(0);

    if (kt < NKT - 3)       asm volatile("s_waitcnt vmcnt(8)" ::: "memory");
    else if (kt == NKT - 3) asm volatile("s_waitcnt vmcnt(4)" ::: "memory");
    else if (kt == NKT - 2) asm volatile("s_waitcnt vmcnt(0)" ::: "memory");
    if (kt < NKT - 1) {
      __builtin_amdgcn_s_barrier();
      asm volatile("" ::: "memory");
    }
  }
#undef STAGE

  const int region = bn0 >> 10;   // 0:u  1:f  2:r
  const int cb0 = bn0 & 1023;
  const int fq = lane >> 4;
  unsigned char* G = (region == 1) ? Fq : Rq;
#pragma unroll
  for (int i = 0; i < 8; i++) {
#pragma unroll
    for (int j = 0; j < 4; j++) {
      const int coln = cb0 + wn * 64 + j * 16 + fr;
      size_t base = (size_t)(bm0 + wm * 128 + i * 16 + fq * 4) * DIM + coln;
      if (region == 0) {
#pragma unroll
        for (int r = 0; r < 4; r++)
          U[base + (size_t)r * DIM] = f2bf(acc[i][j][r]);
      } else {
#pragma unroll
        for (int r = 0; r < 4; r++) {
          float v = fminf(fmaxf(acc[i][j][r] * (1.0f / 6.0f) + 0.5f, 0.0f), 1.0f);
          G[base + (size_t)r * DIM] = (unsigned char)(v * 255.0f + 0.5f);
        }
      }
    }
  }
}

// ---------------- 3) single-pass fused scan (decoupled lookback) ----------------
// 256 blocks = NCHUNK(32) x BATCH(8); block (g,s): thread tid owns channels
// (batch s, d = 4*tid..4*tid+3). status[blk]: 0 none, 1 aggregate ready,
// 2 inclusive ready. Lookback chain: (g-1,s), (g-2,s), ... terminates at g==0
// (publishes inclusive directly). Deterministic result; device-scope
// atomics + threadfence per G16. status memset to 0 before each launch.
__global__ __launch_bounds__(256) void scan_fused(const unsigned short* __restrict__ U,
                                                  const unsigned char* __restrict__ Fq,
                                                  const unsigned char* __restrict__ Rq,
                                                  const float* __restrict__ x,
                                                  const float* __restrict__ cinit,
                                                  const float* __restrict__ muA,
                                                  const float* __restrict__ rsA,
                                                  const float* __restrict__ gamma,
                                                  const float* __restrict__ beta,
                                                  float* __restrict__ aggA,
                                                  float* __restrict__ aggB,
                                                  float* __restrict__ inc,
                                                  int* __restrict__ status,
                                                  float* __restrict__ out,
                                                  float* __restrict__ clast) {
  const int blk = blockIdx.x;
  const int g = blk >> 3;        // chunk
  const int s = blk & 7;         // batch row
  const int tid = threadIdx.x;
  const int d0 = tid * 4;
  const int ch = s * DIM + d0;   // channel base in [0, B*D)

  // ---- phase 1: local aggregate (A = prod f, B) over chunk g ----
  const size_t base = (size_t)(g * CLEN) * (BATCH * DIM) + (size_t)s * DIM + d0;
  float Aa0 = 1.0f, Aa1 = 1.0f, Aa2 = 1.0f, Aa3 = 1.0f;
  float Bb0 = 0.0f, Bb1 = 0.0f, Bb2 = 0.0f, Bb3 = 0.0f;
  {
    size_t off = base;
#pragma unroll 4
    for (int t = 0; t < CLEN; t++) {
      const ushort4 uu = *reinterpret_cast<const ushort4*>(&U[off]);
      const uchar4 ff = *reinterpret_cast<const uchar4*>(&Fq[off]);
      const float f0 = ff.x * (1.0f / 255.0f), f1 = ff.y * (1.0f / 255.0f);
      const float f2 = ff.z * (1.0f / 255.0f), f3 = ff.w * (1.0f / 255.0f);
      Aa0 *= f0; Aa1 *= f1; Aa2 *= f2; Aa3 *= f3;
      Bb0 = f0 * Bb0 + (1.0f - f0) * bf2f(uu.x);
      Bb1 = f1 * Bb1 + (1.0f - f1) * bf2f(uu.y);
      Bb2 = f2 * Bb2 + (1.0f - f2) * bf2f(uu.z);
      Bb3 = f3 * Bb3 + (1.0f - f3) * bf2f(uu.w);
      off += BATCH * DIM;
    }
  }

  __shared__ int sh_st;
  float cs0, cs1, cs2, cs3;
  if (g == 0) {
    const float4 cv = *reinterpret_cast<const float4*>(&cinit[ch]);
    cs0 = cv.x; cs1 = cv.y; cs2 = cv.z; cs3 = cv.w;
  } else {
    // publish aggregate, then look back
    const int go = g * (BATCH * DIM) + ch;
    *reinterpret_cast<float4*>(&aggA[go]) = make_float4(Aa0, Aa1, Aa2, Aa3);
    *reinterpret_cast<float4*>(&aggB[go]) = make_float4(Bb0, Bb1, Bb2, Bb3);
    __threadfence();
    __syncthreads();
    if (tid == 0)
      __hip_atomic_store(&status[blk], 1, __ATOMIC_RELEASE, __HIP_MEMORY_SCOPE_AGENT);

    // lookback: cs = Ka * (value at start of chunk j+1) + Kb
    float Ka0 = 1.0f, Ka1 = 1.0f, Ka2 = 1.0f, Ka3 = 1.0f;
    float Kb0 = 0.0f, Kb1 = 0.0f, Kb2 = 0.0f, Kb3 = 0.0f;
    int j = g - 1;
    for (;;) {
      if (tid == 0) {
        int v;
        do {
          v = __hip_atomic_load(&status[j * 8 + s], __ATOMIC_ACQUIRE,
                                __HIP_MEMORY_SCOPE_AGENT);
          if (v == 0) __builtin_amdgcn_s_sleep(2);
        } while (v == 0);
        sh_st = v;
      }
      __syncthreads();
      const int v = sh_st;
      __syncthreads();
      const int jo = j * (BATCH * DIM) + ch;
      if (v == 2) {
        const float4 iv = *reinterpret_cast<const float4*>(&inc[jo]);
        cs0 = Ka0 * iv.x + Kb0; cs1 = Ka1 * iv.y + Kb1;
        cs2 = Ka2 * iv.z + Kb2; cs3 = Ka3 * iv.w + Kb3;
        break;
      }
      const float4 av = *reinterpret_cast<const float4*>(&aggA[jo]);
      const float4 bv = *reinterpret_cast<const float4*>(&aggB[jo]);
      Kb0 = Ka0 * bv.x + Kb0; Ka0 = Ka0 * av.x;
      Kb1 = Ka1 * bv.y + Kb1; Ka1 = Ka1 * av.y;
      Kb2 = Ka2 * bv.z + Kb2; Ka2 = Ka2 * av.z;
      Kb3 = Ka3 * bv.w + Kb3; Ka3 = Ka3 * av.w;
      --j;   // terminates: j==0 publishes status 2
    }
  }

  // publish inclusive (end-of-chunk value from true start)
  const float i0 = Aa0 * cs0 + Bb0, i1 = Aa1 * cs1 + Bb1;
  const float i2 = Aa2 * cs2 + Bb2, i3 = Aa3 * cs3 + Bb3;
  if (g < NCHUNK - 1) {
    const int go = g * (BATCH * DIM) + ch;
    *reinterpret_cast<float4*>(&inc[go]) = make_float4(i0, i1, i2, i3);
    __threadfence();
    __syncthreads();
    if (tid == 0)
      __hip_atomic_store(&status[blk], 2, __ATOMIC_RELEASE, __HIP_MEMORY_SCOPE_AGENT);
  } else {
    *reinterpret_cast<float4*>(&clast[ch]) = make_float4(i0, i1, i2, i3);
  }

  // ---- phase 2: within-chunk recurrence + epilogue ----
  float c0 = cs0, c1 = cs1, c2 = cs2, c3 = cs3;
  const float4 gm = *reinterpret_cast<const float4*>(&gamma[d0]);
  const float4 bt = *reinterpret_cast<const float4*>(&beta[d0]);
  size_t xo = base;
  int row = g * CLEN * BATCH + s;
#pragma unroll 2
  for (int t = 0; t < CLEN; t++) {
    const ushort4 uu = *reinterpret_cast<const ushort4*>(&U[xo]);
    const uchar4 ff = *reinterpret_cast<const uchar4*>(&Fq[xo]);
    const uchar4 rr = *reinterpret_cast<const uchar4*>(&Rq[xo]);
    const float4 xv = *reinterpret_cast<const float4*>(&x[xo]);
    const float mu = muA[row], rs = rsA[row];
    float o[4];
    {
      const float f = ff.x * (1.0f / 255.0f), r = rr.x * (1.0f / 255.0f);
      const float xnv = (xv.x - mu) * rs * gm.x + bt.x;
      c0 = f * c0 + (1.0f - f) * bf2f(uu.x);
      o[0] = xv.x + r * (c0 / (1.0f + fabsf(c0))) + (1.0f - r) * xnv;
    }
    {
      const float f = ff.y * (1.0f / 255.0f), r = rr.y * (1.0f / 255.0f);
      const float xnv = (xv.y - mu) * rs * gm.y + bt.y;
      c1 = f * c1 + (1.0f - f) * bf2f(uu.y);
      o[1] = xv.y + r * (c1 / (1.0f + fabsf(c1))) + (1.0f - r) * xnv;
    }
    {
      const float f = ff.z * (1.0f / 255.0f), r = rr.z * (1.0f / 255.0f);
      const float xnv = (xv.z - mu) * rs * gm.z + bt.z;
      c2 = f * c2 + (1.0f - f) * bf2f(uu.z);
      o[2] = xv.z + r * (c2 / (1.0f + fabsf(c2))) + (1.0f - r) * xnv;
    }
    {
      const float f = ff.w * (1.0f / 255.0f), r = rr.w * (1.0f / 255.0f);
      const float xnv = (xv.w - mu) * rs * gm.w + bt.w;
      c3 = f * c3 + (1.0f - f) * bf2f(uu.w);
      o[3] = xv.w + r * (c3 / (1.0f + fabsf(c3))) + (1.0f - r) * xnv;
    }
    *reinterpret_cast<float4*>(&out[xo]) = make_float4(o[0], o[1], o[2], o[3]);
    xo += BATCH * DIM;
    row += BATCH;
  }
}

extern "C" void kernel_launch(void* const* d_in, const int* in_sizes, int n_in,
                              void* d_out, int out_size, void* d_ws, size_t ws_size,
                              hipStream_t stream) {
  const float* x = (const float*)d_in[0];
  const float* c0 = (const float*)d_in[1];
  const float* w = (const float*)d_in[2];
  const float* gamma = (const float*)d_in[3];
  const float* beta = (const float*)d_in[4];
  float* out = (float*)d_out;
  float* clast = out + (size_t)M_SZ * DIM;   // second output, flat-concatenated

  // workspace layout (~110.3 MB)
  char* ws = (char*)d_ws;
  unsigned short* xn = (unsigned short*)ws;                        //  33,554,432 B
  unsigned short* U  = (unsigned short*)(ws + 33554432ull);        //  33,554,432 B
  unsigned char* Fq  = (unsigned char*)(ws + 67108864ull);         //  16,777,216 B
  unsigned char* Rq  = (unsigned char*)(ws + 83886080ull);         //  16,777,216 B
  float* aggA = (float*)(ws + 100663296ull);                       //   1,048,576 B
  float* aggB = (float*)(ws + 101711872ull);                       //   1,048,576 B
  float* inc  = (float*)(ws + 102760448ull);                       //   1,048,576 B
  unsigned short* wb = (unsigned short*)(ws + 103809024ull);       //   6,291,456 B
  float* muA = (float*)(ws + 110100480ull);                        //      65,536 B
  float* rsA = (float*)(ws + 110166016ull);                        //      65,536 B
  int* status = (int*)(ws + 110231552ull);                         //       1,024 B

  hipMemsetAsync(status, 0, NCHUNK * BATCH * sizeof(int), stream);
  prep_kernel<<<CVT_BLOCKS + M_SZ, 256, 0, stream>>>(w, wb, x, gamma, beta, xn, muA, rsA);
  gemm_kernel<<<NWG, 512, 0, stream>>>(xn, wb, U, Fq, Rq);
  scan_fused<<<NCHUNK * BATCH, 256, 0, stream>>>(U, Fq, Rq, x, c0, muA, rsA,
                                                 gamma, beta, aggA, aggB, inc,
                                                 status, out, clast);
}

// Round 9
// 244.504 us; speedup vs baseline: 1.0926x; 1.0926x over previous
//
#include <hip/hip_runtime.h>
#include <stdint.h>

// SRU layer fused pipeline (round 9):
//  1) prep:  fused [cvt: w_ufr f32->bf16] + [ln -> x_norm bf16 + mu/rstd]
//  2) gemm:  r7-verified 256x256 / BK=32 / 4-slot ring / counted vmcnt /
//            XOR swizzle / XCD block swizzle. u->bf16, f/r->hardsigmoid u8.
//  3) scan:  single-pass fused scan, AGGREGATE-ONLY decoupled protocol:
//            block (g,s) publishes (A,B) once; waits for all j<g aggregates
//            IN PARALLEL (thread t polls predecessor t — no serial chain);
//            composes chunk-start c locally; then recurrence + epilogue.
//            r8's failure was the 31-hop inclusive chain (~2.5 us/hop);
//            this has exactly ONE wait round-trip on the critical path.

#define T_SEQ 2048
#define BATCH 8
#define DIM 1024
#define M_SZ (T_SEQ * BATCH)   // 16384
#define N_SZ (3 * DIM)         // 3072
#define K_SZ DIM               // 1024
#define NCHUNK 32
#define CLEN (T_SEQ / NCHUNK)  // 64

#define GBM 256
#define GBN 256
#define GBK 32
#define NKT (K_SZ / GBK)          // 32 K-steps
#define NBX (N_SZ / GBN)          // 12
#define NWG (NBX * (M_SZ / GBM))  // 768; 768 % 8 == 0 -> bijective XCD swizzle

#define CVT_BLOCKS ((N_SZ * K_SZ / 4) / 256)   // 3072

typedef __attribute__((ext_vector_type(8))) __bf16 bf16x8;
typedef __attribute__((ext_vector_type(4))) float f32x4;

__device__ __forceinline__ unsigned short f2bf(float f) {
  unsigned int u = __float_as_uint(f);
  u += 0x7FFFu + ((u >> 16) & 1u);   // round-to-nearest-even
  return (unsigned short)(u >> 16);
}
__device__ __forceinline__ float bf2f(unsigned short s) {
  return __uint_as_float(((unsigned int)s) << 16);
}
__device__ __forceinline__ void gload16(const void* g, void* l) {
  __builtin_amdgcn_global_load_lds(
      (__attribute__((address_space(1))) void*)const_cast<void*>(g),
      (__attribute__((address_space(3))) void*)l, 16, 0, 0);
}

// ---------------- 1) fused weight-cvt + LayerNorm ----------------
__global__ __launch_bounds__(256) void prep_kernel(const float* __restrict__ w,
                                                   unsigned short* __restrict__ wb,
                                                   const float* __restrict__ x,
                                                   const float* __restrict__ gamma,
                                                   const float* __restrict__ beta,
                                                   unsigned short* __restrict__ xn,
                                                   float* __restrict__ muO,
                                                   float* __restrict__ rsO) {
  const int tid = threadIdx.x;
  if (blockIdx.x < CVT_BLOCKS) {
    const int i = blockIdx.x * 256 + tid;
    const float4 v = reinterpret_cast<const float4*>(w)[i];
    ushort4 o;
    o.x = f2bf(v.x); o.y = f2bf(v.y); o.z = f2bf(v.z); o.w = f2bf(v.w);
    reinterpret_cast<ushort4*>(wb)[i] = o;
    return;
  }
  const int row = blockIdx.x - CVT_BLOCKS;
  const float4 v = reinterpret_cast<const float4*>(x + (size_t)row * DIM)[tid];
  float s = v.x + v.y + v.z + v.w;
  float q = v.x * v.x + v.y * v.y + v.z * v.z + v.w * v.w;
#pragma unroll
  for (int off = 32; off > 0; off >>= 1) {
    s += __shfl_down(s, off);
    q += __shfl_down(q, off);
  }
  __shared__ float sbuf[8];
  const int wv = tid >> 6, ln = tid & 63;
  if (ln == 0) { sbuf[wv] = s; sbuf[4 + wv] = q; }
  __syncthreads();
  s = sbuf[0] + sbuf[1] + sbuf[2] + sbuf[3];
  q = sbuf[4] + sbuf[5] + sbuf[6] + sbuf[7];
  const float mu = s * (1.0f / DIM);
  const float rstd = rsqrtf(q * (1.0f / DIM) - mu * mu + 1e-5f);
  if (tid == 0) { muO[row] = mu; rsO[row] = rstd; }
  const float4 g = reinterpret_cast<const float4*>(gamma)[tid];
  const float4 b = reinterpret_cast<const float4*>(beta)[tid];
  ushort4 o;
  o.x = f2bf((v.x - mu) * rstd * g.x + b.x);
  o.y = f2bf((v.y - mu) * rstd * g.y + b.y);
  o.z = f2bf((v.z - mu) * rstd * g.z + b.z);
  o.w = f2bf((v.w - mu) * rstd * g.w + b.w);
  reinterpret_cast<ushort4*>(xn + (size_t)row * DIM)[tid] = o;
}

// ---------------- 2) GEMM: C[m,n] = sum_k A[m,k] * W[n,k], bf16 MFMA ----------------
// r7-verified. 256x256 tile, BK=32, 512 threads (8 waves, 2Mx4N), 4-slot LDS
// ring, depth-3 prefetch, vmcnt(8) steady state, one s_barrier per K-step,
// XOR slot-swizzle (0 bank conflicts), XCD block swizzle.
__global__ __launch_bounds__(512) void gemm_kernel(const unsigned short* __restrict__ A,
                                                   const unsigned short* __restrict__ W,
                                                   unsigned short* __restrict__ U,
                                                   unsigned char* __restrict__ Fq,
                                                   unsigned char* __restrict__ Rq) {
  __shared__ unsigned short smem[2 * 4 * GBM * GBK];   // 131072 B
  const int tid = threadIdx.x;
  const int lane = tid & 63;
  const int wid = tid >> 6;                 // 0..7
  const int wm = wid >> 2, wn = wid & 3;    // 2 x 4 wave grid

  const int wg = (blockIdx.x & 7) * (NWG / 8) + (blockIdx.x >> 3);
  const int bn0 = (wg % NBX) * GBN;
  const int bm0 = (wg / NBX) * GBM;

  const int stgRow = wid * 32 + (lane >> 2);
  const int stgCol = ((lane & 3) ^ ((lane >> 3) & 3)) * 8;
  const unsigned short* gA = A + (size_t)(bm0 + stgRow) * K_SZ + stgCol;
  const unsigned short* gB = W + (size_t)(bn0 + stgRow) * K_SZ + stgCol;
  unsigned short* sAb = smem + wid * 32 * GBK;
  unsigned short* sBb = smem + 4 * GBM * GBK + wid * 32 * GBK;

#define STAGE(bufi, t) do {                                        \
    const size_t ko_ = (size_t)(t) * GBK;                          \
    unsigned short* sa_ = sAb + (bufi) * (GBM * GBK);              \
    unsigned short* sb_ = sBb + (bufi) * (GBM * GBK);              \
    gload16(gA + ko_, sa_);                                        \
    gload16(gA + ko_ + (size_t)16 * K_SZ, sa_ + 16 * GBK);         \
    gload16(gB + ko_, sb_);                                        \
    gload16(gB + ko_ + (size_t)16 * K_SZ, sb_ + 16 * GBK);         \
  } while (0)

  f32x4 acc[8][4] = {};
  const int fr = lane & 15;
  const int ko8 = ((lane >> 4) ^ ((fr >> 1) & 3)) * 8;

  STAGE(0, 0);
  STAGE(1, 1);
  STAGE(2, 2);
  asm volatile("s_waitcnt vmcnt(8)" ::: "memory");
  __builtin_amdgcn_s_barrier();
  asm volatile("" ::: "memory");

  for (int kt = 0; kt < NKT; ++kt) {
    const int cur = kt & 3;
    if (kt < NKT - 3) STAGE((kt + 3) & 3, kt + 3);

    const unsigned short* sa = smem + cur * (GBM * GBK);
    const unsigned short* sb = smem + 4 * GBM * GBK + cur * (GBM * GBK);
    bf16x8 af[8], bf[4];
#pragma unroll
    for (int i = 0; i < 8; i++)
      af[i] = *(const bf16x8*)&sa[(wm * 128 + i * 16 + fr) * GBK + ko8];
#pragma unroll
    for (int j = 0; j < 4; j++)
      bf[j] = *(const bf16x8*)&sb[(wn * 64 + j * 16 + fr) * GBK + ko8];

    __builtin_amdgcn_s_setprio(1);
#pragma unroll
    for (int i = 0; i < 8; i++)
#pragma unroll
      for (int j = 0; j < 4; j++)
        acc[i][j] = __builtin_amdgcn_mfma_f32_16x16x32_bf16(af[i], bf[j], acc[i][j], 0, 0, 0);
    __builtin_amdgcn_s_setprio(0);

    if (kt < NKT - 3)       asm volatile("s_waitcnt vmcnt(8)" ::: "memory");
    else if (kt == NKT - 3) asm volatile("s_waitcnt vmcnt(4)" ::: "memory");
    else if (kt == NKT - 2) asm volatile("s_waitcnt vmcnt(0)" ::: "memory");
    if (kt < NKT - 1) {
      __builtin_amdgcn_s_barrier();
      asm volatile("" ::: "memory");
    }
  }
#undef STAGE

  const int region = bn0 >> 10;   // 0:u  1:f  2:r
  const int cb0 = bn0 & 1023;
  const int fq = lane >> 4;
  unsigned char* G = (region == 1) ? Fq : Rq;
#pragma unroll
  for (int i = 0; i < 8; i++) {
#pragma unroll
    for (int j = 0; j < 4; j++) {
      const int coln = cb0 + wn * 64 + j * 16 + fr;
      size_t base = (size_t)(bm0 + wm * 128 + i * 16 + fq * 4) * DIM + coln;
      if (region == 0) {
#pragma unroll
        for (int r = 0; r < 4; r++)
          U[base + (size_t)r * DIM] = f2bf(acc[i][j][r]);
      } else {
#pragma unroll
        for (int r = 0; r < 4; r++) {
          float v = fminf(fmaxf(acc[i][j][r] * (1.0f / 6.0f) + 0.5f, 0.0f), 1.0f);
          G[base + (size_t)r * DIM] = (unsigned char)(v * 255.0f + 0.5f);
        }
      }
    }
  }
}

// ---------------- 3) single-pass fused scan (aggregate-only protocol) -------
// 256 blocks = NCHUNK(32) x BATCH(8). Block (g,s), thread tid owns channels
// (s, 4*tid..4*tid+3). Protocol:
//   phase 1: local (A = prod f, B) over chunk g; publish to agg[g]; release
//            status[blk]=1.
//   wait:    thread t (t < g) polls status[t*8+s] until 1 — ALL predecessors
//            polled in parallel, one round-trip, no chain. __syncthreads.
//   compose: every thread folds cs = A_j*cs + B_j for j=0..g-1 (L2 reads).
//   phase 2: within-chunk recurrence + softsign + mix + residual; block 31
//            writes c_last.
// Deadlock-free: waits only on lower block ids; grid (256 wg, 4 waves, 36
// VGPR) fully co-resident on 256 CUs. Deterministic math: composition order
// is fixed j=0..g-1 regardless of arrival timing.
__global__ __launch_bounds__(256) void scan_fused(const unsigned short* __restrict__ U,
                                                  const unsigned char* __restrict__ Fq,
                                                  const unsigned char* __restrict__ Rq,
                                                  const float* __restrict__ x,
                                                  const float* __restrict__ cinit,
                                                  const float* __restrict__ muA,
                                                  const float* __restrict__ rsA,
                                                  const float* __restrict__ gamma,
                                                  const float* __restrict__ beta,
                                                  float* __restrict__ aggA,
                                                  float* __restrict__ aggB,
                                                  int* __restrict__ status,
                                                  float* __restrict__ out,
                                                  float* __restrict__ clast) {
  const int blk = blockIdx.x;
  const int g = blk >> 3;        // chunk
  const int s = blk & 7;         // batch row
  const int tid = threadIdx.x;
  const int d0 = tid * 4;
  const int ch = s * DIM + d0;   // channel base in [0, B*D)

  // ---- phase 1: local aggregate (A = prod f, B) over chunk g ----
  const size_t base = (size_t)(g * CLEN) * (BATCH * DIM) + (size_t)s * DIM + d0;
  float Aa0 = 1.0f, Aa1 = 1.0f, Aa2 = 1.0f, Aa3 = 1.0f;
  float Bb0 = 0.0f, Bb1 = 0.0f, Bb2 = 0.0f, Bb3 = 0.0f;
  {
    size_t off = base;
#pragma unroll 4
    for (int t = 0; t < CLEN; t++) {
      const ushort4 uu = *reinterpret_cast<const ushort4*>(&U[off]);
      const uchar4 ff = *reinterpret_cast<const uchar4*>(&Fq[off]);
      const float f0 = ff.x * (1.0f / 255.0f), f1 = ff.y * (1.0f / 255.0f);
      const float f2 = ff.z * (1.0f / 255.0f), f3 = ff.w * (1.0f / 255.0f);
      Aa0 *= f0; Aa1 *= f1; Aa2 *= f2; Aa3 *= f3;
      Bb0 = f0 * Bb0 + (1.0f - f0) * bf2f(uu.x);
      Bb1 = f1 * Bb1 + (1.0f - f1) * bf2f(uu.y);
      Bb2 = f2 * Bb2 + (1.0f - f2) * bf2f(uu.z);
      Bb3 = f3 * Bb3 + (1.0f - f3) * bf2f(uu.w);
      off += BATCH * DIM;
    }
  }

  // publish aggregate (blocks g < NCHUNK-1 have successors; publish anyway
  // for uniformity — cost is one 32 KB L2 write per block)
  float cs0, cs1, cs2, cs3;
  {
    const int go = g * (BATCH * DIM) + ch;
    *reinterpret_cast<float4*>(&aggA[go]) = make_float4(Aa0, Aa1, Aa2, Aa3);
    *reinterpret_cast<float4*>(&aggB[go]) = make_float4(Bb0, Bb1, Bb2, Bb3);
    __threadfence();
    __syncthreads();
    if (tid == 0)
      __hip_atomic_store(&status[blk], 1, __ATOMIC_RELEASE, __HIP_MEMORY_SCOPE_AGENT);

    // parallel wait: thread t < g polls predecessor chunk t (same s)
    if (tid < g) {
      while (__hip_atomic_load(&status[tid * 8 + s], __ATOMIC_ACQUIRE,
                               __HIP_MEMORY_SCOPE_AGENT) == 0)
        __builtin_amdgcn_s_sleep(2);
    }
    __syncthreads();
    asm volatile("" ::: "memory");

    // local composition, fixed order j = 0 .. g-1
    const float4 cv = *reinterpret_cast<const float4*>(&cinit[ch]);
    cs0 = cv.x; cs1 = cv.y; cs2 = cv.z; cs3 = cv.w;
    for (int j = 0; j < g; ++j) {
      const int jo = j * (BATCH * DIM) + ch;
      const float4 av = *reinterpret_cast<const float4*>(&aggA[jo]);
      const float4 bv = *reinterpret_cast<const float4*>(&aggB[jo]);
      cs0 = av.x * cs0 + bv.x;
      cs1 = av.y * cs1 + bv.y;
      cs2 = av.z * cs2 + bv.z;
      cs3 = av.w * cs3 + bv.w;
    }
  }

  if (g == NCHUNK - 1) {
    const float i0 = Aa0 * cs0 + Bb0, i1 = Aa1 * cs1 + Bb1;
    const float i2 = Aa2 * cs2 + Bb2, i3 = Aa3 * cs3 + Bb3;
    *reinterpret_cast<float4*>(&clast[ch]) = make_float4(i0, i1, i2, i3);
  }

  // ---- phase 2: within-chunk recurrence + epilogue ----
  float c0 = cs0, c1 = cs1, c2 = cs2, c3 = cs3;
  const float4 gm = *reinterpret_cast<const float4*>(&gamma[d0]);
  const float4 bt = *reinterpret_cast<const float4*>(&beta[d0]);
  size_t xo = base;
  int row = g * CLEN * BATCH + s;
#pragma unroll 2
  for (int t = 0; t < CLEN; t++) {
    const ushort4 uu = *reinterpret_cast<const ushort4*>(&U[xo]);
    const uchar4 ff = *reinterpret_cast<const uchar4*>(&Fq[xo]);
    const uchar4 rr = *reinterpret_cast<const uchar4*>(&Rq[xo]);
    const float4 xv = *reinterpret_cast<const float4*>(&x[xo]);
    const float mu = muA[row], rs = rsA[row];
    float o[4];
    {
      const float f = ff.x * (1.0f / 255.0f), r = rr.x * (1.0f / 255.0f);
      const float xnv = (xv.x - mu) * rs * gm.x + bt.x;
      c0 = f * c0 + (1.0f - f) * bf2f(uu.x);
      o[0] = xv.x + r * (c0 / (1.0f + fabsf(c0))) + (1.0f - r) * xnv;
    }
    {
      const float f = ff.y * (1.0f / 255.0f), r = rr.y * (1.0f / 255.0f);
      const float xnv = (xv.y - mu) * rs * gm.y + bt.y;
      c1 = f * c1 + (1.0f - f) * bf2f(uu.y);
      o[1] = xv.y + r * (c1 / (1.0f + fabsf(c1))) + (1.0f - r) * xnv;
    }
    {
      const float f = ff.z * (1.0f / 255.0f), r = rr.z * (1.0f / 255.0f);
      const float xnv = (xv.z - mu) * rs * gm.z + bt.z;
      c2 = f * c2 + (1.0f - f) * bf2f(uu.z);
      o[2] = xv.z + r * (c2 / (1.0f + fabsf(c2))) + (1.0f - r) * xnv;
    }
    {
      const float f = ff.w * (1.0f / 255.0f), r = rr.w * (1.0f / 255.0f);
      const float xnv = (xv.w - mu) * rs * gm.w + bt.w;
      c3 = f * c3 + (1.0f - f) * bf2f(uu.w);
      o[3] = xv.w + r * (c3 / (1.0f + fabsf(c3))) + (1.0f - r) * xnv;
    }
    *reinterpret_cast<float4*>(&out[xo]) = make_float4(o[0], o[1], o[2], o[3]);
    xo += BATCH * DIM;
    row += BATCH;
  }
}

extern "C" void kernel_launch(void* const* d_in, const int* in_sizes, int n_in,
                              void* d_out, int out_size, void* d_ws, size_t ws_size,
                              hipStream_t stream) {
  const float* x = (const float*)d_in[0];
  const float* c0 = (const float*)d_in[1];
  const float* w = (const float*)d_in[2];
  const float* gamma = (const float*)d_in[3];
  const float* beta = (const float*)d_in[4];
  float* out = (float*)d_out;
  float* clast = out + (size_t)M_SZ * DIM;   // second output, flat-concatenated

  // workspace layout (~110.3 MB)
  char* ws = (char*)d_ws;
  unsigned short* xn = (unsigned short*)ws;                        //  33,554,432 B
  unsigned short* U  = (unsigned short*)(ws + 33554432ull);        //  33,554,432 B
  unsigned char* Fq  = (unsigned char*)(ws + 67108864ull);         //  16,777,216 B
  unsigned char* Rq  = (unsigned char*)(ws + 83886080ull);         //  16,777,216 B
  float* aggA = (float*)(ws + 100663296ull);                       //   1,048,576 B
  float* aggB = (float*)(ws + 101711872ull);                       //   1,048,576 B
  unsigned short* wb = (unsigned short*)(ws + 103809024ull);       //   6,291,456 B
  float* muA = (float*)(ws + 110100480ull);                        //      65,536 B
  float* rsA = (float*)(ws + 110166016ull);                        //      65,536 B
  int* status = (int*)(ws + 110231552ull);                         //       1,024 B

  hipMemsetAsync(status, 0, NCHUNK * BATCH * sizeof(int), stream);
  prep_kernel<<<CVT_BLOCKS + M_SZ, 256, 0, stream>>>(w, wb, x, gamma, beta, xn, muA, rsA);
  gemm_kernel<<<NWG, 512, 0, stream>>>(xn, wb, U, Fq, Rq);
  scan_fused<<<NCHUNK * BATCH, 256, 0, stream>>>(U, Fq, Rq, x, c0, muA, rsA,
                                                 gamma, beta, aggA, aggB,
                                                 status, out, clast);
}

// Round 10
// 184.652 us; speedup vs baseline: 1.4468x; 1.3241x over previous
//
#include <hip/hip_runtime.h>
#include <stdint.h>

// SRU layer fused pipeline (round 10) — r7 trio + finer chunking + prep fusion:
//  1) prep:  fused [cvt: w_ufr f32->bf16] + [ln -> x_norm bf16 + mu/rstd]
//  2) gemm:  r7-verified 256x256 / BK=32 / 4-slot ring / counted vmcnt /
//            XOR swizzle (0 conflicts) / XCD block swizzle. u->bf16 [M][D],
//            f/r->hardsigmoid u8 [M][D].
//  3) scan1: per-chunk (A = prod f, B) composition — NCHUNK=128, CLEN=16,
//            1024 blocks (4/CU) for proper latency hiding
//  4) scan2: sequential scan over 128 chunks -> chunk-start c, c_last
//  5) scan3: within-chunk recurrence + epilogue — 4-wide, f32 x_norm
//            recompute, 1024 blocks
// r8/r9 lesson: persistent fused scan (decoupled lookback) loses ~50 us to
// cross-XCD fence/poll traffic — the 3-kernel trio with L3-hot re-reads wins.

#define T_SEQ 2048
#define BATCH 8
#define DIM 1024
#define M_SZ (T_SEQ * BATCH)   // 16384
#define N_SZ (3 * DIM)         // 3072
#define K_SZ DIM               // 1024
#define NCHUNK 128
#define CLEN (T_SEQ / NCHUNK)  // 16

#define GBM 256
#define GBN 256
#define GBK 32
#define NKT (K_SZ / GBK)          // 32 K-steps
#define NBX (N_SZ / GBN)          // 12
#define NWG (NBX * (M_SZ / GBM))  // 768; 768 % 8 == 0 -> bijective XCD swizzle

#define CVT_BLOCKS ((N_SZ * K_SZ / 4) / 256)   // 3072

typedef __attribute__((ext_vector_type(8))) __bf16 bf16x8;
typedef __attribute__((ext_vector_type(4))) float f32x4;

__device__ __forceinline__ unsigned short f2bf(float f) {
  unsigned int u = __float_as_uint(f);
  u += 0x7FFFu + ((u >> 16) & 1u);   // round-to-nearest-even
  return (unsigned short)(u >> 16);
}
__device__ __forceinline__ float bf2f(unsigned short s) {
  return __uint_as_float(((unsigned int)s) << 16);
}
__device__ __forceinline__ void gload16(const void* g, void* l) {
  __builtin_amdgcn_global_load_lds(
      (__attribute__((address_space(1))) void*)const_cast<void*>(g),
      (__attribute__((address_space(3))) void*)l, 16, 0, 0);
}

// ---------------- 1) fused weight-cvt + LayerNorm ----------------
__global__ __launch_bounds__(256) void prep_kernel(const float* __restrict__ w,
                                                   unsigned short* __restrict__ wb,
                                                   const float* __restrict__ x,
                                                   const float* __restrict__ gamma,
                                                   const float* __restrict__ beta,
                                                   unsigned short* __restrict__ xn,
                                                   float* __restrict__ muO,
                                                   float* __restrict__ rsO) {
  const int tid = threadIdx.x;
  if (blockIdx.x < CVT_BLOCKS) {
    const int i = blockIdx.x * 256 + tid;
    const float4 v = reinterpret_cast<const float4*>(w)[i];
    ushort4 o;
    o.x = f2bf(v.x); o.y = f2bf(v.y); o.z = f2bf(v.z); o.w = f2bf(v.w);
    reinterpret_cast<ushort4*>(wb)[i] = o;
    return;
  }
  const int row = blockIdx.x - CVT_BLOCKS;
  const float4 v = reinterpret_cast<const float4*>(x + (size_t)row * DIM)[tid];
  float s = v.x + v.y + v.z + v.w;
  float q = v.x * v.x + v.y * v.y + v.z * v.z + v.w * v.w;
#pragma unroll
  for (int off = 32; off > 0; off >>= 1) {
    s += __shfl_down(s, off);
    q += __shfl_down(q, off);
  }
  __shared__ float sbuf[8];
  const int wv = tid >> 6, ln = tid & 63;
  if (ln == 0) { sbuf[wv] = s; sbuf[4 + wv] = q; }
  __syncthreads();
  s = sbuf[0] + sbuf[1] + sbuf[2] + sbuf[3];
  q = sbuf[4] + sbuf[5] + sbuf[6] + sbuf[7];
  const float mu = s * (1.0f / DIM);
  const float rstd = rsqrtf(q * (1.0f / DIM) - mu * mu + 1e-5f);
  if (tid == 0) { muO[row] = mu; rsO[row] = rstd; }
  const float4 g = reinterpret_cast<const float4*>(gamma)[tid];
  const float4 b = reinterpret_cast<const float4*>(beta)[tid];
  ushort4 o;
  o.x = f2bf((v.x - mu) * rstd * g.x + b.x);
  o.y = f2bf((v.y - mu) * rstd * g.y + b.y);
  o.z = f2bf((v.z - mu) * rstd * g.z + b.z);
  o.w = f2bf((v.w - mu) * rstd * g.w + b.w);
  reinterpret_cast<ushort4*>(xn + (size_t)row * DIM)[tid] = o;
}

// ---------------- 2) GEMM: C[m,n] = sum_k A[m,k] * W[n,k], bf16 MFMA ----------------
// r7-verified. 256x256 tile, BK=32, 512 threads (8 waves, 2Mx4N), 4-slot LDS
// ring, depth-3 prefetch, vmcnt(8) steady state, one s_barrier per K-step,
// XOR slot-swizzle (0 bank conflicts), XCD block swizzle.
__global__ __launch_bounds__(512) void gemm_kernel(const unsigned short* __restrict__ A,
                                                   const unsigned short* __restrict__ W,
                                                   unsigned short* __restrict__ U,
                                                   unsigned char* __restrict__ Fq,
                                                   unsigned char* __restrict__ Rq) {
  __shared__ unsigned short smem[2 * 4 * GBM * GBK];   // 131072 B
  const int tid = threadIdx.x;
  const int lane = tid & 63;
  const int wid = tid >> 6;                 // 0..7
  const int wm = wid >> 2, wn = wid & 3;    // 2 x 4 wave grid

  const int wg = (blockIdx.x & 7) * (NWG / 8) + (blockIdx.x >> 3);
  const int bn0 = (wg % NBX) * GBN;
  const int bm0 = (wg / NBX) * GBM;

  const int stgRow = wid * 32 + (lane >> 2);
  const int stgCol = ((lane & 3) ^ ((lane >> 3) & 3)) * 8;
  const unsigned short* gA = A + (size_t)(bm0 + stgRow) * K_SZ + stgCol;
  const unsigned short* gB = W + (size_t)(bn0 + stgRow) * K_SZ + stgCol;
  unsigned short* sAb = smem + wid * 32 * GBK;
  unsigned short* sBb = smem + 4 * GBM * GBK + wid * 32 * GBK;

#define STAGE(bufi, t) do {                                        \
    const size_t ko_ = (size_t)(t) * GBK;                          \
    unsigned short* sa_ = sAb + (bufi) * (GBM * GBK);              \
    unsigned short* sb_ = sBb + (bufi) * (GBM * GBK);              \
    gload16(gA + ko_, sa_);                                        \
    gload16(gA + ko_ + (size_t)16 * K_SZ, sa_ + 16 * GBK);         \
    gload16(gB + ko_, sb_);                                        \
    gload16(gB + ko_ + (size_t)16 * K_SZ, sb_ + 16 * GBK);         \
  } while (0)

  f32x4 acc[8][4] = {};
  const int fr = lane & 15;
  const int ko8 = ((lane >> 4) ^ ((fr >> 1) & 3)) * 8;

  STAGE(0, 0);
  STAGE(1, 1);
  STAGE(2, 2);
  asm volatile("s_waitcnt vmcnt(8)" ::: "memory");
  __builtin_amdgcn_s_barrier();
  asm volatile("" ::: "memory");

  for (int kt = 0; kt < NKT; ++kt) {
    const int cur = kt & 3;
    if (kt < NKT - 3) STAGE((kt + 3) & 3, kt + 3);

    const unsigned short* sa = smem + cur * (GBM * GBK);
    const unsigned short* sb = smem + 4 * GBM * GBK + cur * (GBM * GBK);
    bf16x8 af[8], bf[4];
#pragma unroll
    for (int i = 0; i < 8; i++)
      af[i] = *(const bf16x8*)&sa[(wm * 128 + i * 16 + fr) * GBK + ko8];
#pragma unroll
    for (int j = 0; j < 4; j++)
      bf[j] = *(const bf16x8*)&sb[(wn * 64 + j * 16 + fr) * GBK + ko8];

    __builtin_amdgcn_s_setprio(1);
#pragma unroll
    for (int i = 0; i < 8; i++)
#pragma unroll
      for (int j = 0; j < 4; j++)
        acc[i][j] = __builtin_amdgcn_mfma_f32_16x16x32_bf16(af[i], bf[j], acc[i][j], 0, 0, 0);
    __builtin_amdgcn_s_setprio(0);

    if (kt < NKT - 3)       asm volatile("s_waitcnt vmcnt(8)" ::: "memory");
    else if (kt == NKT - 3) asm volatile("s_waitcnt vmcnt(4)" ::: "memory");
    else if (kt == NKT - 2) asm volatile("s_waitcnt vmcnt(0)" ::: "memory");
    if (kt < NKT - 1) {
      __builtin_amdgcn_s_barrier();
      asm volatile("" ::: "memory");
    }
  }
#undef STAGE

  const int region = bn0 >> 10;   // 0:u  1:f  2:r
  const int cb0 = bn0 & 1023;
  const int fq = lane >> 4;
  unsigned char* G = (region == 1) ? Fq : Rq;
#pragma unroll
  for (int i = 0; i < 8; i++) {
#pragma unroll
    for (int j = 0; j < 4; j++) {
      const int coln = cb0 + wn * 64 + j * 16 + fr;
      size_t base = (size_t)(bm0 + wm * 128 + i * 16 + fq * 4) * DIM + coln;
      if (region == 0) {
#pragma unroll
        for (int r = 0; r < 4; r++)
          U[base + (size_t)r * DIM] = f2bf(acc[i][j][r]);
      } else {
#pragma unroll
        for (int r = 0; r < 4; r++) {
          float v = fminf(fmaxf(acc[i][j][r] * (1.0f / 6.0f) + 0.5f, 0.0f), 1.0f);
          G[base + (size_t)r * DIM] = (unsigned char)(v * 255.0f + 0.5f);
        }
      }
    }
  }
}

// ---------------- 3) per-chunk recurrence composition (4-wide) ----------------
// NCHUNK=128 -> 1024 blocks (4/CU, 16 waves/CU) for latency hiding.
__global__ __launch_bounds__(256) void scan1_kernel(const unsigned short* __restrict__ U,
                                                    const unsigned char* __restrict__ Fq,
                                                    float* __restrict__ Ac,
                                                    float* __restrict__ Bc) {
  const int lin = blockIdx.x * 256 + threadIdx.x;   // NCHUNK*B*D/4 = 262144
  const int d0 = (lin & 255) << 2;
  const int b = (lin >> 8) & (BATCH - 1);
  const int g = lin >> 11;
  size_t off = (size_t)(g * CLEN) * (BATCH * DIM) + (size_t)b * DIM + d0;
  float Aa0 = 1.0f, Aa1 = 1.0f, Aa2 = 1.0f, Aa3 = 1.0f;
  float Bb0 = 0.0f, Bb1 = 0.0f, Bb2 = 0.0f, Bb3 = 0.0f;
#pragma unroll 4
  for (int t = 0; t < CLEN; t++) {
    const ushort4 uu = *reinterpret_cast<const ushort4*>(&U[off]);
    const uchar4 ff = *reinterpret_cast<const uchar4*>(&Fq[off]);
    const float f0 = ff.x * (1.0f / 255.0f), f1 = ff.y * (1.0f / 255.0f);
    const float f2 = ff.z * (1.0f / 255.0f), f3 = ff.w * (1.0f / 255.0f);
    Aa0 *= f0; Aa1 *= f1; Aa2 *= f2; Aa3 *= f3;
    Bb0 = f0 * Bb0 + (1.0f - f0) * bf2f(uu.x);
    Bb1 = f1 * Bb1 + (1.0f - f1) * bf2f(uu.y);
    Bb2 = f2 * Bb2 + (1.0f - f2) * bf2f(uu.z);
    Bb3 = f3 * Bb3 + (1.0f - f3) * bf2f(uu.w);
    off += BATCH * DIM;
  }
  const int o = g * (BATCH * DIM) + b * DIM + d0;
  *reinterpret_cast<float4*>(&Ac[o]) = make_float4(Aa0, Aa1, Aa2, Aa3);
  *reinterpret_cast<float4*>(&Bc[o]) = make_float4(Bb0, Bb1, Bb2, Bb3);
}

// ---------------- 4) scan over chunks ----------------
__global__ __launch_bounds__(256) void scan2_kernel(const float* __restrict__ Ac,
                                                    const float* __restrict__ Bc,
                                                    const float* __restrict__ c0,
                                                    float* __restrict__ cstart,
                                                    float* __restrict__ clast) {
  const int lin = blockIdx.x * 256 + threadIdx.x;   // B*D = 8192
  float c = c0[lin];
  for (int g = 0; g < NCHUNK; g++) {
    cstart[g * (BATCH * DIM) + lin] = c;
    c = Ac[g * (BATCH * DIM) + lin] * c + Bc[g * (BATCH * DIM) + lin];
  }
  clast[lin] = c;
}

// ---------------- 5) within-chunk recurrence + epilogue (4-wide, f32 x_norm) --
__global__ __launch_bounds__(256) void scan3_kernel(const unsigned short* __restrict__ U,
                                                    const unsigned char* __restrict__ Fq,
                                                    const unsigned char* __restrict__ Rq,
                                                    const float* __restrict__ x,
                                                    const float* __restrict__ cstart,
                                                    const float* __restrict__ muA,
                                                    const float* __restrict__ rsA,
                                                    const float* __restrict__ gamma,
                                                    const float* __restrict__ beta,
                                                    float* __restrict__ out) {
  const int lin = blockIdx.x * 256 + threadIdx.x;   // NCHUNK*B*D/4 = 262144
  const int d0 = (lin & 255) << 2;
  const int b = (lin >> 8) & (BATCH - 1);
  const int g = lin >> 11;
  const float4 cs = *reinterpret_cast<const float4*>(&cstart[g * (BATCH * DIM) + b * DIM + d0]);
  float c0 = cs.x, c1 = cs.y, c2 = cs.z, c3 = cs.w;
  const float4 gm = *reinterpret_cast<const float4*>(&gamma[d0]);
  const float4 bt = *reinterpret_cast<const float4*>(&beta[d0]);
  size_t xo = (size_t)(g * CLEN) * (BATCH * DIM) + (size_t)b * DIM + d0;
  int row = g * CLEN * BATCH + b;
#pragma unroll 4
  for (int t = 0; t < CLEN; t++) {
    const ushort4 uu = *reinterpret_cast<const ushort4*>(&U[xo]);
    const uchar4 ff = *reinterpret_cast<const uchar4*>(&Fq[xo]);
    const uchar4 rr = *reinterpret_cast<const uchar4*>(&Rq[xo]);
    const float4 xv = *reinterpret_cast<const float4*>(&x[xo]);
    const float mu = muA[row], rs = rsA[row];
    float o[4];
    {
      const float f = ff.x * (1.0f / 255.0f), r = rr.x * (1.0f / 255.0f);
      const float xnv = (xv.x - mu) * rs * gm.x + bt.x;
      c0 = f * c0 + (1.0f - f) * bf2f(uu.x);
      o[0] = xv.x + r * (c0 / (1.0f + fabsf(c0))) + (1.0f - r) * xnv;
    }
    {
      const float f = ff.y * (1.0f / 255.0f), r = rr.y * (1.0f / 255.0f);
      const float xnv = (xv.y - mu) * rs * gm.y + bt.y;
      c1 = f * c1 + (1.0f - f) * bf2f(uu.y);
      o[1] = xv.y + r * (c1 / (1.0f + fabsf(c1))) + (1.0f - r) * xnv;
    }
    {
      const float f = ff.z * (1.0f / 255.0f), r = rr.z * (1.0f / 255.0f);
      const float xnv = (xv.z - mu) * rs * gm.z + bt.z;
      c2 = f * c2 + (1.0f - f) * bf2f(uu.z);
      o[2] = xv.z + r * (c2 / (1.0f + fabsf(c2))) + (1.0f - r) * xnv;
    }
    {
      const float f = ff.w * (1.0f / 255.0f), r = rr.w * (1.0f / 255.0f);
      const float xnv = (xv.w - mu) * rs * gm.w + bt.w;
      c3 = f * c3 + (1.0f - f) * bf2f(uu.w);
      o[3] = xv.w + r * (c3 / (1.0f + fabsf(c3))) + (1.0f - r) * xnv;
    }
    *reinterpret_cast<float4*>(&out[xo]) = make_float4(o[0], o[1], o[2], o[3]);
    xo += BATCH * DIM;
    row += BATCH;
  }
}

extern "C" void kernel_launch(void* const* d_in, const int* in_sizes, int n_in,
                              void* d_out, int out_size, void* d_ws, size_t ws_size,
                              hipStream_t stream) {
  const float* x = (const float*)d_in[0];
  const float* c0 = (const float*)d_in[1];
  const float* w = (const float*)d_in[2];
  const float* gamma = (const float*)d_in[3];
  const float* beta = (const float*)d_in[4];
  float* out = (float*)d_out;
  float* clast = out + (size_t)M_SZ * DIM;   // second output, flat-concatenated

  // workspace layout (~119.7 MB)
  char* ws = (char*)d_ws;
  unsigned short* xn = (unsigned short*)ws;                        //  33,554,432 B
  unsigned short* U  = (unsigned short*)(ws + 33554432ull);        //  33,554,432 B
  unsigned char* Fq  = (unsigned char*)(ws + 67108864ull);         //  16,777,216 B
  unsigned char* Rq  = (unsigned char*)(ws + 83886080ull);         //  16,777,216 B
  float* Ac = (float*)(ws + 100663296ull);                         //   4,194,304 B
  float* Bc = (float*)(ws + 104857600ull);                         //   4,194,304 B
  float* cst = (float*)(ws + 109051904ull);                        //   4,194,304 B
  unsigned short* wb = (unsigned short*)(ws + 113246208ull);       //   6,291,456 B
  float* muA = (float*)(ws + 119537664ull);                        //      65,536 B
  float* rsA = (float*)(ws + 119603200ull);                        //      65,536 B

  prep_kernel<<<CVT_BLOCKS + M_SZ, 256, 0, stream>>>(w, wb, x, gamma, beta, xn, muA, rsA);
  gemm_kernel<<<NWG, 512, 0, stream>>>(xn, wb, U, Fq, Rq);
  scan1_kernel<<<(NCHUNK * BATCH * DIM / 4) / 256, 256, 0, stream>>>(U, Fq, Ac, Bc);
  scan2_kernel<<<(BATCH * DIM) / 256, 256, 0, stream>>>(Ac, Bc, c0, cst, clast);
  scan3_kernel<<<(NCHUNK * BATCH * DIM / 4) / 256, 256, 0, stream>>>(
      U, Fq, Rq, x, cst, muA, rsA, gamma, beta, out);
}